// Round 7
// baseline (472.071 us; speedup 1.0000x reference)
//
#include <hip/hip_runtime.h>

#ifndef __has_builtin
#define __has_builtin(x) 0
#endif

#define T_STEPS 512
#define BATCH   128
#define DIN     256
#define HID     256
#define WPLD    (DIN + HID)   // 512

typedef float v2f __attribute__((ext_vector_type(2)));

// Volatile asm load: result is NOT rematerializable -> must stay in VGPRs.
#define ASM_LOAD4(dst, ptr) \
    asm volatile("global_load_dwordx4 %0, %1, off" : "=v"(dst) : "v"(ptr))

// ---------------- cross-lane helpers ----------------
template<int CTRL>
__device__ __forceinline__ float dppmov(float x) {
    // 0xB1=quad xor1, 0x4E=quad xor2, 0x124=row_ror:4, 0x128=row_ror:8
    return __int_as_float(__builtin_amdgcn_update_dpp(0, __float_as_int(x), CTRL, 0xF, 0xF, true));
}
template<int PAT>
__device__ __forceinline__ float swz(float x) {
    return __int_as_float(__builtin_amdgcn_ds_swizzle(__float_as_int(x), PAT));
}
__device__ __forceinline__ float lane_xor16(float v, int l) {
#if __has_builtin(__builtin_amdgcn_permlane16_swap)
    auto r = __builtin_amdgcn_permlane16_swap(__float_as_uint(v), __float_as_uint(v), false, false);
    return __uint_as_float((l & 16) ? r[0] : r[1]);
#else
    return swz<0x401F>(v);
#endif
}
__device__ __forceinline__ float lane_xor32(float v, int l) {
#if __has_builtin(__builtin_amdgcn_permlane32_swap)
    auto r = __builtin_amdgcn_permlane32_swap(__float_as_uint(v), __float_as_uint(v), false, false);
    return __uint_as_float((l & 32) ? r[0] : r[1]);
#else
    return __shfl_xor(v, 32);
#endif
}
__device__ __forceinline__ float rcp_f(float x) {
#if __has_builtin(__builtin_amdgcn_rcpf)
    return __builtin_amdgcn_rcpf(x);
#else
    return 1.0f / x;
#endif
}
__device__ __forceinline__ v2f fma2(v2f a, v2f b, v2f c) {
#if __has_builtin(__builtin_elementwise_fma)
    return __builtin_elementwise_fma(a, b, c);
#else
    return (v2f){fmaf(a.x, b.x, c.x), fmaf(a.y, b.y, c.y)};
#endif
}
__device__ __forceinline__ v2f expv(v2f x) { return (v2f){__expf(x.x), __expf(x.y)}; }
__device__ __forceinline__ v2f rcpv(v2f x) { return (v2f){rcp_f(x.x), rcp_f(x.y)}; }
__device__ __forceinline__ v2f clampv(v2f x, float lo, float hi) {
    return (v2f){fminf(fmaxf(x.x, lo), hi), fminf(fmaxf(x.y, lo), hi)};
}

// fused LSTM pointwise on a pair of elements: 5 exp + 2 rcp per element
__device__ __forceinline__ v2f lstm2(v2f f, v2f i, v2f g, v2f o, v2f& c) {
    v2f a    = expv(-f);
    v2f bb   = expv(-i);
    v2f d    = expv(2.f * g);
    v2f onea = 1.f + a, oneb = 1.f + bb, dp = d + 1.f, dm = d - 1.f;
    v2f num  = c * oneb * dp + dm * onea;
    v2f den  = onea * oneb * dp;
    v2f cn   = num * rcpv(den);
    v2f cnc  = clampv(cn, -15.f, 15.f);
    v2f u    = expv(2.f * cnc);
    v2f eo   = expv(-o);
    v2f h    = (u - 1.f) * rcpv((1.f + eo) * (u + 1.f));
    c = cn;
    return h;
}

// ---------------------------------------------------------------------------
// Kernel 1: px[b][t][q] = sum_d x[t,b,d]*Wp[q,d] + qp[q]
// ---------------------------------------------------------------------------
__global__ __launch_bounds__(256) void qlstm_projx(const float* __restrict__ x,
                                                   const float* __restrict__ Wp,
                                                   const float* __restrict__ qp,
                                                   float* __restrict__ px) {
    const int wave = threadIdx.x >> 6;
    const int lane = threadIdx.x & 63;
    const int row  = blockIdx.x * 4 + wave;       // row = t*BATCH + b

    const float4 xv = ((const float4*)(x + (size_t)row * DIN))[lane];
    float acc[8];
#pragma unroll
    for (int Q = 0; Q < 8; ++Q) {
        float4 w = ((const float4*)(Wp + Q * WPLD))[lane];
        acc[Q] = xv.x * w.x + xv.y * w.y + xv.z * w.z + xv.w * w.w;
    }
#pragma unroll
    for (int Q = 0; Q < 8; ++Q) {
        acc[Q] += dppmov<0xB1>(acc[Q]);
        acc[Q] += dppmov<0x4E>(acc[Q]);
        acc[Q] += swz<0x101F>(acc[Q]);
    }
    float p = acc[0];
#pragma unroll
    for (int j = 1; j < 8; ++j) p = ((lane & 7) == j) ? acc[j] : p;
    p += swz<0x201F>(p);
    p += swz<0x401F>(p);
    p += __shfl_xor(p, 32);
    if (lane < 8) {
        const int bb = row & (BATCH - 1);
        const int tt = row >> 7;
        px[(size_t)bb * (T_STEPS * 8) + tt * 8 + lane] = p + qp[lane];
    }
}

// ---------------------------------------------------------------------------
// Kernel 2: recurrence. One wave per batch row; h/c in registers; no barriers.
// ALL weights loaded via volatile-asm global loads -> cannot be rematerialized
// -> guaranteed register-resident across the 512-step loop.
// ---------------------------------------------------------------------------
__global__ __launch_bounds__(64, 1) void qlstm_seq(const float* __restrict__ hx,
                                                   const float* __restrict__ cx,
                                                   const float* __restrict__ Wp,
                                                   const float* __restrict__ Wg,
                                                   const float* __restrict__ bg,
                                                   const float* __restrict__ px,
                                                   float* __restrict__ out) {
    __shared__ float px_lds[(T_STEPS + 1) * 8];   // +8 pad for prefetch overrun

    const int l = threadIdx.x;
    const int b = blockIdx.x;

    // preload all px for this b (4096 floats)
    {
        const float4* pg = (const float4*)(px + (size_t)b * (T_STEPS * 8));
        float4* pl = (float4*)px_lds;
#pragma unroll
        for (int j = 0; j < 16; ++j) pl[j * 64 + l] = pg[j * 64 + l];
    }

    // ---- asm-resident weight loads (44 x dwordx4) ----
    float4 WPH[8];        // WPH[q] = Wp[q][256+4l .. +3]
#pragma unroll
    for (int q = 0; q < 8; ++q) {
        const float* a = Wp + q * WPLD + DIN + 4 * l;
        ASM_LOAD4(WPH[q], a);
    }
    float4 WGv[4][4][2];  // [G][e][half]: Wg row (G*256+4l+e), floats 0..7
#pragma unroll
    for (int G = 0; G < 4; ++G)
#pragma unroll
        for (int e = 0; e < 4; ++e) {
            const float* r = Wg + (size_t)(G * HID + 4 * l + e) * 8;
            ASM_LOAD4(WGv[G][e][0], r);
            ASM_LOAD4(WGv[G][e][1], r + 4);
        }
    float4 BGv[4];        // bg[G*256+4l .. +3]
#pragma unroll
    for (int G = 0; G < 4; ++G) {
        const float* a = bg + G * HID + 4 * l;
        ASM_LOAD4(BGv[G], a);
    }
    asm volatile("s_waitcnt vmcnt(0)" ::: "memory");
    __builtin_amdgcn_sched_barrier(0);   // rule #18: no hoisting past the waitcnt

    // repack to v2f (register-subword moves, cheap, done once)
    v2f wph2[8][2];
#pragma unroll
    for (int q = 0; q < 8; ++q) {
        wph2[q][0] = (v2f){WPH[q].x, WPH[q].y};
        wph2[q][1] = (v2f){WPH[q].z, WPH[q].w};
    }
    v2f wg2[4][4][4];
    float bgr[4][4];
#pragma unroll
    for (int G = 0; G < 4; ++G)
#pragma unroll
        for (int e = 0; e < 4; ++e) {
            wg2[G][e][0] = (v2f){WGv[G][e][0].x, WGv[G][e][0].y};
            wg2[G][e][1] = (v2f){WGv[G][e][0].z, WGv[G][e][0].w};
            wg2[G][e][2] = (v2f){WGv[G][e][1].x, WGv[G][e][1].y};
            wg2[G][e][3] = (v2f){WGv[G][e][1].z, WGv[G][e][1].w};
        }
#pragma unroll
    for (int G = 0; G < 4; ++G) {
        bgr[G][0] = BGv[G].x; bgr[G][1] = BGv[G].y;
        bgr[G][2] = BGv[G].z; bgr[G][3] = BGv[G].w;
    }

    // state: this lane owns h[4l..4l+3], c[4l..4l+3]
    float4 h4 = *(const float4*)(hx + b * HID + 4 * l);
    float4 c4 = *(const float4*)(cx + b * HID + 4 * l);
    v2f hv[2] = {(v2f){h4.x, h4.y}, (v2f){h4.z, h4.w}};
    v2f cc[2] = {(v2f){c4.x, c4.y}, (v2f){c4.z, c4.w}};

    __syncthreads();   // px_lds ready (single wave; trivial)

    // prefetch px for t=0
    float4 pxa = *(const float4*)(&px_lds[0]);
    float4 pxb = *(const float4*)(&px_lds[4]);

    float* outp = out + (size_t)b * HID + 4 * l;

    for (int t = 0; t < T_STEPS; ++t) {
        // per-lane partial dot: s[q] = sum_e h_own[e] * Wp[q, 256+4l+e]
        float s[8];
#pragma unroll
        for (int q = 0; q < 8; ++q) {
            v2f a = hv[0] * wph2[q][0];
            a = fma2(hv[1], wph2[q][1], a);
            s[q] = a.x + a.y;
        }
        // all-VALU 64-lane allreduce (verified chain from R2)
#pragma unroll
        for (int q = 0; q < 8; ++q) {
            float v = s[q];
            v += dppmov<0xB1>(v);        // xor1
            v += dppmov<0x4E>(v);        // xor2
            v += dppmov<0x124>(v);       // ror4
            v += dppmov<0x128>(v);       // ror8
            v += lane_xor16(v, l);
            v += lane_xor32(v, l);
            s[q] = v;
        }

        // prefetch px for t+1
        float4 nxa = *(const float4*)(&px_lds[(t + 1) * 8]);
        float4 nxb = *(const float4*)(&px_lds[(t + 1) * 8 + 4]);

        const float C0 = __cosf(s[0] + pxa.x);
        const float C1 = __cosf(s[1] + pxa.y);
        const float C2 = __cosf(s[2] + pxa.z);
        const float C3 = __cosf(s[3] + pxa.w);
        const float C4 = __cosf(s[4] + pxb.x);
        const float C5 = __cosf(s[5] + pxb.y);
        const float C6 = __cosf(s[6] + pxb.z);
        const float C7 = __cosf(s[7] + pxb.w);

        // prefix products: qo[0]=C1..C7, qo[k>=1]=C0..Ck
        const float d01 = C0 * C1, d23 = C2 * C3, d45 = C4 * C5, d67 = C6 * C7;
        const float q1 = d01;
        const float q2 = d01 * C2;
        const float q3 = d01 * d23;
        const float q4 = q3 * C4;
        const float q5 = q3 * d45;
        const float q6 = q5 * C6;
        const float q7 = q5 * d67;
        const float q0 = (C1 * d23) * (d45 * d67);

        const v2f qv[4] = {(v2f){q0, q1}, (v2f){q2, q3}, (v2f){q4, q5}, (v2f){q6, q7}};

        // gates: 4 gates x 4 elements, packed FMA over the 8-dim qo
        float g[4][4];
#pragma unroll
        for (int G = 0; G < 4; ++G)
#pragma unroll
            for (int e = 0; e < 4; ++e) {
                v2f acc = (v2f){bgr[G][e], 0.f};
                acc = fma2(wg2[G][e][0], qv[0], acc);
                acc = fma2(wg2[G][e][1], qv[1], acc);
                acc = fma2(wg2[G][e][2], qv[2], acc);
                acc = fma2(wg2[G][e][3], qv[3], acc);
                g[G][e] = acc.x + acc.y;
            }

        const v2f fg0 = (v2f){g[0][0], g[0][1]}, fg1 = (v2f){g[0][2], g[0][3]};
        const v2f ig0 = (v2f){g[1][0], g[1][1]}, ig1 = (v2f){g[1][2], g[1][3]};
        const v2f gg0 = (v2f){g[2][0], g[2][1]}, gg1 = (v2f){g[2][2], g[2][3]};
        const v2f og0 = (v2f){g[3][0], g[3][1]}, og1 = (v2f){g[3][2], g[3][3]};

        hv[0] = lstm2(fg0, ig0, gg0, og0, cc[0]);
        hv[1] = lstm2(fg1, ig1, gg1, og1, cc[1]);

        *(float4*)outp = make_float4(hv[0].x, hv[0].y, hv[1].x, hv[1].y);
        outp += BATCH * HID;
        pxa = nxa;
        pxb = nxb;
    }

    const size_t base = (size_t)T_STEPS * BATCH * HID;
    *(float4*)(out + base + b * HID + 4 * l) =
        make_float4(hv[0].x, hv[0].y, hv[1].x, hv[1].y);
    *(float4*)(out + base + BATCH * HID + b * HID + 4 * l) =
        make_float4(cc[0].x, cc[0].y, cc[1].x, cc[1].y);
}

extern "C" void kernel_launch(void* const* d_in, const int* in_sizes, int n_in,
                              void* d_out, int out_size, void* d_ws, size_t ws_size,
                              hipStream_t stream) {
    const float* x   = (const float*)d_in[0];   // (512,128,256)
    const float* hx  = (const float*)d_in[1];   // (128,256)
    const float* cx  = (const float*)d_in[2];   // (128,256)
    const float* Wp  = (const float*)d_in[3];   // (8,512)
    const float* qp  = (const float*)d_in[4];   // (8,)
    const float* Wg  = (const float*)d_in[5];   // (1024,8)
    const float* bg  = (const float*)d_in[6];   // (1024,)
    float* out = (float*)d_out;
    float* px  = (float*)d_ws;                  // 128*512*8 floats = 2 MB

    qlstm_projx<<<(T_STEPS * BATCH) / 4, 256, 0, stream>>>(x, Wp, qp, px);
    qlstm_seq<<<BATCH, 64, 0, stream>>>(hx, cx, Wp, Wg, bg, px, out);
}

// Round 8
// 387.803 us; speedup vs baseline: 1.2173x; 1.2173x over previous
//
#include <hip/hip_runtime.h>

#ifndef __has_builtin
#define __has_builtin(x) 0
#endif

#define T_STEPS 512
#define BATCH   128
#define DIN     256
#define HID     256
#define WPLD    (DIN + HID)   // 512

// Volatile asm loads: results are NOT rematerializable -> must stay resident.
#define ASM_LOAD4(dst, ptr) \
    asm volatile("global_load_dwordx4 %0, %1, off" : "=v"(dst) : "v"(ptr))
#define ASM_LOAD1(dst, ptr) \
    asm volatile("global_load_dword %0, %1, off" : "=v"(dst) : "v"(ptr))

// ---------------- cross-lane helpers ----------------
template<int CTRL>
__device__ __forceinline__ float dppmov(float x) {
    // 0xB1=quad xor1, 0x4E=quad xor2, 0x124=row_ror:4, 0x128=row_ror:8
    return __int_as_float(__builtin_amdgcn_update_dpp(0, __float_as_int(x), CTRL, 0xF, 0xF, true));
}
template<int PAT>
__device__ __forceinline__ float swz(float x) {
    return __int_as_float(__builtin_amdgcn_ds_swizzle(__float_as_int(x), PAT));
}
__device__ __forceinline__ float lane_xor16(float v, int l) {
#if __has_builtin(__builtin_amdgcn_permlane16_swap)
    auto r = __builtin_amdgcn_permlane16_swap(__float_as_uint(v), __float_as_uint(v), false, false);
    return __uint_as_float((l & 16) ? r[0] : r[1]);
#else
    return swz<0x401F>(v);
#endif
}
__device__ __forceinline__ float lane_xor32(float v, int l) {
#if __has_builtin(__builtin_amdgcn_permlane32_swap)
    auto r = __builtin_amdgcn_permlane32_swap(__float_as_uint(v), __float_as_uint(v), false, false);
    return __uint_as_float((l & 32) ? r[0] : r[1]);
#else
    return __shfl_xor(v, 32);
#endif
}
__device__ __forceinline__ float rcp_f(float x) {
#if __has_builtin(__builtin_amdgcn_rcpf)
    return __builtin_amdgcn_rcpf(x);
#else
    return 1.0f / x;
#endif
}

// ---------------------------------------------------------------------------
// Kernel 1: px[b][t][q] = sum_d x[t,b,d]*Wp[q,d] + qp[q]
// ---------------------------------------------------------------------------
__global__ __launch_bounds__(256) void qlstm_projx(const float* __restrict__ x,
                                                   const float* __restrict__ Wp,
                                                   const float* __restrict__ qp,
                                                   float* __restrict__ px) {
    const int wave = threadIdx.x >> 6;
    const int lane = threadIdx.x & 63;
    const int row  = blockIdx.x * 4 + wave;       // row = t*BATCH + b

    const float4 xv = ((const float4*)(x + (size_t)row * DIN))[lane];
    float acc[8];
#pragma unroll
    for (int Q = 0; Q < 8; ++Q) {
        float4 w = ((const float4*)(Wp + Q * WPLD))[lane];
        acc[Q] = xv.x * w.x + xv.y * w.y + xv.z * w.z + xv.w * w.w;
    }
#pragma unroll
    for (int Q = 0; Q < 8; ++Q) {
        acc[Q] += dppmov<0xB1>(acc[Q]);
        acc[Q] += dppmov<0x4E>(acc[Q]);
        acc[Q] += swz<0x101F>(acc[Q]);
    }
    float p = acc[0];
#pragma unroll
    for (int j = 1; j < 8; ++j) p = ((lane & 7) == j) ? acc[j] : p;
    p += swz<0x201F>(p);
    p += swz<0x401F>(p);
    p += __shfl_xor(p, 32);
    if (lane < 8) {
        const int bb = row & (BATCH - 1);
        const int tt = row >> 7;
        px[(size_t)bb * (T_STEPS * 8) + tt * 8 + lane] = p + qp[lane];
    }
}

// ---------------------------------------------------------------------------
// Kernel 2: recurrence. One block (4 waves / 4 SIMDs) per batch row; lane owns
// ONE column. Weights via volatile-asm loads (non-rematerializable) and
// __launch_bounds__(256,1) (full VGPR budget) -> guaranteed register-resident.
// Cross-wave combine: in-wave DPP allreduce -> lane0 publishes 8 partials ->
// one barrier (double-buffered) -> broadcast read.
// ---------------------------------------------------------------------------
__global__ __launch_bounds__(256, 1) void qlstm_seq(const float* __restrict__ hx,
                                                    const float* __restrict__ cx,
                                                    const float* __restrict__ Wp,
                                                    const float* __restrict__ Wg,
                                                    const float* __restrict__ bg,
                                                    const float* __restrict__ px,
                                                    float* __restrict__ out) {
    __shared__ float px_lds[(T_STEPS + 1) * 8];   // 16 KB (+pad for prefetch overrun)
    __shared__ float part[2][4][8];               // double-buffered wave partials

    const int tid = threadIdx.x;
    const int w   = tid >> 6;     // wave id 0..3
    const int l   = tid & 63;     // lane
    const int b   = blockIdx.x;
    const int col = tid;          // this lane's h/c column (0..255)

    // ---- asm-resident weight loads (issued first; latency hidden by staging) ----
    float wph[8];                 // Wp[q][256+col]
#pragma unroll
    for (int q = 0; q < 8; ++q) {
        const float* a = Wp + q * WPLD + DIN + col;
        ASM_LOAD1(wph[q], a);
    }
    float4 WG0[4], WG1[4];        // Wg row (G*256+col), floats 0..7
#pragma unroll
    for (int G = 0; G < 4; ++G) {
        const float* r = Wg + (size_t)(G * HID + col) * 8;
        ASM_LOAD4(WG0[G], r);
        ASM_LOAD4(WG1[G], r + 4);
    }
    float bgc[4];                 // bg[G*256+col]
#pragma unroll
    for (int G = 0; G < 4; ++G) {
        const float* a = bg + G * HID + col;
        ASM_LOAD1(bgc[G], a);
    }

    // preload all px for this b (4096 floats = 1024 float4, 4 per thread)
    {
        const float4* pg = (const float4*)(px + (size_t)b * (T_STEPS * 8));
        float4* pl = (float4*)px_lds;
#pragma unroll
        for (int j = 0; j < 4; ++j) pl[j * 256 + tid] = pg[j * 256 + tid];
    }

    float h = hx[b * HID + col];
    float c = cx[b * HID + col];

    asm volatile("s_waitcnt vmcnt(0)" ::: "memory");
    __builtin_amdgcn_sched_barrier(0);   // rule #18: nothing hoists above the wait
    __syncthreads();                      // px_lds ready

    // prefetch px for t=0
    float4 pxa = *(const float4*)(&px_lds[0]);
    float4 pxb = *(const float4*)(&px_lds[4]);

    float* outp = out + (size_t)b * HID + col;

    for (int t = 0; t < T_STEPS; ++t) {
        // per-lane partials p[q] = h*wph[q]; in-wave 64-lane allreduce
        float s[8];
#pragma unroll
        for (int q = 0; q < 8; ++q) {
            float v = h * wph[q];
            v += dppmov<0xB1>(v);        // xor1   (fused DPP add)
            v += dppmov<0x4E>(v);        // xor2
            v += dppmov<0x124>(v);       // ror4   (rotation-allreduce)
            v += dppmov<0x128>(v);       // ror8
            v += lane_xor16(v, l);
            v += lane_xor32(v, l);
            s[q] = v;
        }

        // lane 0 of each wave publishes its wave's 8 partial sums
        if (l == 0) {
            *(float4*)&part[t & 1][w][0] = make_float4(s[0], s[1], s[2], s[3]);
            *(float4*)&part[t & 1][w][4] = make_float4(s[4], s[5], s[6], s[7]);
        }
        __syncthreads();   // single barrier per step (double-buffered part)

        // sum the 4 waves' partials (broadcast reads, conflict-free)
        const float4* pp = (const float4*)&part[t & 1][0][0];
        const float4 a0 = pp[0], b0 = pp[1], a1 = pp[2], b1 = pp[3];
        const float4 a2 = pp[4], b2 = pp[5], a3 = pp[6], b3 = pp[7];
        const float SA0 = a0.x + a1.x + a2.x + a3.x;
        const float SA1 = a0.y + a1.y + a2.y + a3.y;
        const float SA2 = a0.z + a1.z + a2.z + a3.z;
        const float SA3 = a0.w + a1.w + a2.w + a3.w;
        const float SB0 = b0.x + b1.x + b2.x + b3.x;
        const float SB1 = b0.y + b1.y + b2.y + b3.y;
        const float SB2 = b0.z + b1.z + b2.z + b3.z;
        const float SB3 = b0.w + b1.w + b2.w + b3.w;

        const float C0 = __cosf(SA0 + pxa.x);
        const float C1 = __cosf(SA1 + pxa.y);
        const float C2 = __cosf(SA2 + pxa.z);
        const float C3 = __cosf(SA3 + pxa.w);
        const float C4 = __cosf(SB0 + pxb.x);
        const float C5 = __cosf(SB1 + pxb.y);
        const float C6 = __cosf(SB2 + pxb.z);
        const float C7 = __cosf(SB3 + pxb.w);

        // prefetch px for t+1
        pxa = *(const float4*)(&px_lds[(t + 1) * 8]);
        pxb = *(const float4*)(&px_lds[(t + 1) * 8 + 4]);

        // prefix products: qo[0]=C1..C7, qo[k>=1]=C0..Ck
        const float d01 = C0 * C1, d23 = C2 * C3, d45 = C4 * C5, d67 = C6 * C7;
        float qo[8];
        qo[1] = d01;
        qo[2] = d01 * C2;
        qo[3] = d01 * d23;
        qo[4] = qo[3] * C4;
        qo[5] = qo[3] * d45;
        qo[6] = qo[5] * C6;
        qo[7] = qo[5] * d67;
        qo[0] = (C1 * d23) * (d45 * d67);

        // gates for this lane's single column (weights in registers)
        float gf = bgc[0], gi = bgc[1], gg = bgc[2], go = bgc[3];
        gf = fmaf(WG0[0].x, qo[0], gf); gf = fmaf(WG0[0].y, qo[1], gf);
        gf = fmaf(WG0[0].z, qo[2], gf); gf = fmaf(WG0[0].w, qo[3], gf);
        gf = fmaf(WG1[0].x, qo[4], gf); gf = fmaf(WG1[0].y, qo[5], gf);
        gf = fmaf(WG1[0].z, qo[6], gf); gf = fmaf(WG1[0].w, qo[7], gf);
        gi = fmaf(WG0[1].x, qo[0], gi); gi = fmaf(WG0[1].y, qo[1], gi);
        gi = fmaf(WG0[1].z, qo[2], gi); gi = fmaf(WG0[1].w, qo[3], gi);
        gi = fmaf(WG1[1].x, qo[4], gi); gi = fmaf(WG1[1].y, qo[5], gi);
        gi = fmaf(WG1[1].z, qo[6], gi); gi = fmaf(WG1[1].w, qo[7], gi);
        gg = fmaf(WG0[2].x, qo[0], gg); gg = fmaf(WG0[2].y, qo[1], gg);
        gg = fmaf(WG0[2].z, qo[2], gg); gg = fmaf(WG0[2].w, qo[3], gg);
        gg = fmaf(WG1[2].x, qo[4], gg); gg = fmaf(WG1[2].y, qo[5], gg);
        gg = fmaf(WG1[2].z, qo[6], gg); gg = fmaf(WG1[2].w, qo[7], gg);
        go = fmaf(WG0[3].x, qo[0], go); go = fmaf(WG0[3].y, qo[1], go);
        go = fmaf(WG0[3].z, qo[2], go); go = fmaf(WG0[3].w, qo[3], go);
        go = fmaf(WG1[3].x, qo[4], go); go = fmaf(WG1[3].y, qo[5], go);
        go = fmaf(WG1[3].z, qo[6], go); go = fmaf(WG1[3].w, qo[7], go);

        // scalar LSTM pointwise: 5 exp + 2 rcp
        const float ea = __expf(-gf);               // sigmoid(f) = 1/(1+ea)
        const float eb = __expf(-gi);               // sigmoid(i) = 1/(1+eb)
        const float d  = __expf(2.f * gg);          // tanh(g) = (d-1)/(d+1)
        const float onea = 1.f + ea, oneb = 1.f + eb, dp = d + 1.f;
        const float num = c * oneb * dp + (d - 1.f) * onea;
        const float den = onea * oneb * dp;
        const float cn  = num * rcp_f(den);
        const float cnc = fminf(fmaxf(cn, -15.f), 15.f);
        const float u   = __expf(2.f * cnc);
        const float eo  = __expf(-go);
        h = (u - 1.f) * rcp_f((1.f + eo) * (u + 1.f));
        c = cn;

        *outp = h;
        outp += BATCH * HID;
    }

    const size_t base = (size_t)T_STEPS * BATCH * HID;
    out[base + b * HID + col] = h;
    out[base + BATCH * HID + b * HID + col] = c;
}

extern "C" void kernel_launch(void* const* d_in, const int* in_sizes, int n_in,
                              void* d_out, int out_size, void* d_ws, size_t ws_size,
                              hipStream_t stream) {
    const float* x   = (const float*)d_in[0];   // (512,128,256)
    const float* hx  = (const float*)d_in[1];   // (128,256)
    const float* cx  = (const float*)d_in[2];   // (128,256)
    const float* Wp  = (const float*)d_in[3];   // (8,512)
    const float* qp  = (const float*)d_in[4];   // (8,)
    const float* Wg  = (const float*)d_in[5];   // (1024,8)
    const float* bg  = (const float*)d_in[6];   // (1024,)
    float* out = (float*)d_out;
    float* px  = (float*)d_ws;                  // 128*512*8 floats = 2 MB

    qlstm_projx<<<(T_STEPS * BATCH) / 4, 256, 0, stream>>>(x, Wp, qp, px);
    qlstm_seq<<<BATCH, 256, 0, stream>>>(hx, cx, Wp, Wg, bg, px, out);
}

// Round 9
// 354.995 us; speedup vs baseline: 1.3298x; 1.0924x over previous
//
#include <hip/hip_runtime.h>

#ifndef __has_builtin
#define __has_builtin(x) 0
#endif

#define T_STEPS 512
#define BATCH   128
#define DIN     256
#define HID     256
#define WPLD    (DIN + HID)   // 512

// Volatile asm loads: results are NOT rematerializable (cheap insurance).
#define ASM_LOAD4(dst, ptr) \
    asm volatile("global_load_dwordx4 %0, %1, off" : "=v"(dst) : "v"(ptr))
#define ASM_LOAD1(dst, ptr) \
    asm volatile("global_load_dword %0, %1, off" : "=v"(dst) : "v"(ptr))

// ---------------- cross-lane helpers ----------------
template<int CTRL>
__device__ __forceinline__ float dppmov(float x) {
    // 0xB1=quad xor1, 0x4E=quad xor2, 0x124=row_ror:4, 0x128=row_ror:8
    return __int_as_float(__builtin_amdgcn_update_dpp(0, __float_as_int(x), CTRL, 0xF, 0xF, true));
}
template<int PAT>
__device__ __forceinline__ float swz(float x) {
    return __int_as_float(__builtin_amdgcn_ds_swizzle(__float_as_int(x), PAT));
}
__device__ __forceinline__ float lane_xor16(float v, int l) {
#if __has_builtin(__builtin_amdgcn_permlane16_swap)
    auto r = __builtin_amdgcn_permlane16_swap(__float_as_uint(v), __float_as_uint(v), false, false);
    return __uint_as_float((l & 16) ? r[0] : r[1]);
#else
    return swz<0x401F>(v);
#endif
}
__device__ __forceinline__ float lane_xor32(float v, int l) {
#if __has_builtin(__builtin_amdgcn_permlane32_swap)
    auto r = __builtin_amdgcn_permlane32_swap(__float_as_uint(v), __float_as_uint(v), false, false);
    return __uint_as_float((l & 32) ? r[0] : r[1]);
#else
    return __shfl_xor(v, 32);
#endif
}
__device__ __forceinline__ float rcp_f(float x) {
#if __has_builtin(__builtin_amdgcn_rcpf)
    return __builtin_amdgcn_rcpf(x);
#else
    return 1.0f / x;
#endif
}

// ---------------------------------------------------------------------------
// Kernel 1: px[b][t][q] = sum_d x[t,b,d]*Wp[q,d] + qp[q]
// ---------------------------------------------------------------------------
__global__ __launch_bounds__(256) void qlstm_projx(const float* __restrict__ x,
                                                   const float* __restrict__ Wp,
                                                   const float* __restrict__ qp,
                                                   float* __restrict__ px) {
    const int wave = threadIdx.x >> 6;
    const int lane = threadIdx.x & 63;
    const int row  = blockIdx.x * 4 + wave;       // row = t*BATCH + b

    const float4 xv = ((const float4*)(x + (size_t)row * DIN))[lane];
    float acc[8];
#pragma unroll
    for (int Q = 0; Q < 8; ++Q) {
        float4 w = ((const float4*)(Wp + Q * WPLD))[lane];
        acc[Q] = xv.x * w.x + xv.y * w.y + xv.z * w.z + xv.w * w.w;
    }
#pragma unroll
    for (int Q = 0; Q < 8; ++Q) {
        acc[Q] += dppmov<0xB1>(acc[Q]);
        acc[Q] += dppmov<0x4E>(acc[Q]);
        acc[Q] += swz<0x101F>(acc[Q]);
    }
    float p = acc[0];
#pragma unroll
    for (int j = 1; j < 8; ++j) p = ((lane & 7) == j) ? acc[j] : p;
    p += swz<0x201F>(p);
    p += swz<0x401F>(p);
    p += __shfl_xor(p, 32);
    if (lane < 8) {
        const int bb = row & (BATCH - 1);
        const int tt = row >> 7;
        px[(size_t)bb * (T_STEPS * 8) + tt * 8 + lane] = p + qp[lane];
    }
}

// ---------------------------------------------------------------------------
// Kernel 2: recurrence. One block (4 waves) per batch row.
// Every wave computes the FULL 8-dot proj redundantly (lane l holds h[4l..4l+3]
// read from LDS) -> single in-wave allreduce, NO cross-wave partial exchange.
// Wave w owns gate/LSTM columns 64w..64w+63 (one per lane). The only cross-wave
// traffic is the h handoff: 1 ds_write + 1 barrier + 1 ds_read (double-buffered).
// ---------------------------------------------------------------------------
__global__ __launch_bounds__(256, 1) void qlstm_seq(const float* __restrict__ hx,
                                                    const float* __restrict__ cx,
                                                    const float* __restrict__ Wp,
                                                    const float* __restrict__ Wg,
                                                    const float* __restrict__ bg,
                                                    const float* __restrict__ px,
                                                    float* __restrict__ out) {
    __shared__ float px_lds[(T_STEPS + 1) * 8];   // +8 pad for prefetch overrun
    __shared__ float hbuf[2][HID];                // double-buffered h

    const int tid = threadIdx.x;
    const int w   = tid >> 6;     // wave id 0..3
    const int l   = tid & 63;     // lane
    const int b   = blockIdx.x;
    const int cg  = (w << 6) | l; // this thread's gate/LSTM column
    const bool lane0 = (l == 0);

    // ---- weight loads (asm: non-rematerializable) ----
    float4 wph[8];                // Wp[q][256+4l .. +3]  (same for all waves)
#pragma unroll
    for (int q = 0; q < 8; ++q) {
        const float* a = Wp + q * WPLD + DIN + 4 * l;
        ASM_LOAD4(wph[q], a);
    }
    float4 WG0[4], WG1[4];        // Wg row (G*256+cg), floats 0..7
#pragma unroll
    for (int G = 0; G < 4; ++G) {
        const float* r = Wg + (size_t)(G * HID + cg) * 8;
        ASM_LOAD4(WG0[G], r);
        ASM_LOAD4(WG1[G], r + 4);
    }
    float bgc[4];                 // bg[G*256+cg]
#pragma unroll
    for (int G = 0; G < 4; ++G) {
        const float* a = bg + G * HID + cg;
        ASM_LOAD1(bgc[G], a);
    }

    // preload all px for this b (4096 floats = 1024 float4, 4 per thread)
    {
        const float4* pg = (const float4*)(px + (size_t)b * (T_STEPS * 8));
        float4* pl = (float4*)px_lds;
#pragma unroll
        for (int j = 0; j < 4; ++j) pl[j * 256 + tid] = pg[j * 256 + tid];
    }

    float c = cx[b * HID + cg];
    hbuf[0][tid] = hx[b * HID + tid];

    asm volatile("s_waitcnt vmcnt(0)" ::: "memory");
    __builtin_amdgcn_sched_barrier(0);
    __syncthreads();   // hbuf[0] + px_lds ready

    // prefetch px for t=0
    float4 pxa = *(const float4*)(&px_lds[0]);
    float4 pxb = *(const float4*)(&px_lds[4]);

    float* outp = out + (size_t)b * HID + cg;

    for (int t = 0; t < T_STEPS; ++t) {
        // full h for proj: lane l reads h[4l..4l+3] (all waves read same data)
        const float4 h4 = *(const float4*)&hbuf[t & 1][4 * l];

        const float pxv[8] = {pxa.x, pxa.y, pxa.z, pxa.w, pxb.x, pxb.y, pxb.z, pxb.w};

        // per-lane partials (px folded into lane 0's base); full in-wave allreduce
        float s[8];
#pragma unroll
        for (int q = 0; q < 8; ++q) {
            float v = lane0 ? pxv[q] : 0.f;
            v = fmaf(h4.x, wph[q].x, v);
            v = fmaf(h4.y, wph[q].y, v);
            v = fmaf(h4.z, wph[q].z, v);
            v = fmaf(h4.w, wph[q].w, v);
            s[q] = v;
        }
#pragma unroll
        for (int q = 0; q < 8; ++q) {
            float v = s[q];
            v += dppmov<0xB1>(v);        // xor1
            v += dppmov<0x4E>(v);        // xor2
            v += dppmov<0x124>(v);       // ror4
            v += dppmov<0x128>(v);       // ror8 (== xor8 within row16)
            v += lane_xor16(v, l);
            v += lane_xor32(v, l);
            s[q] = v;
        }

        const float C0 = __cosf(s[0]);
        const float C1 = __cosf(s[1]);
        const float C2 = __cosf(s[2]);
        const float C3 = __cosf(s[3]);
        const float C4 = __cosf(s[4]);
        const float C5 = __cosf(s[5]);
        const float C6 = __cosf(s[6]);
        const float C7 = __cosf(s[7]);

        // prefetch px for t+1 (off critical path)
        pxa = *(const float4*)(&px_lds[(t + 1) * 8]);
        pxb = *(const float4*)(&px_lds[(t + 1) * 8 + 4]);

        // prefix products: qo[0]=C1..C7, qo[k>=1]=C0..Ck
        const float d01 = C0 * C1, d23 = C2 * C3, d45 = C4 * C5, d67 = C6 * C7;
        float qo[8];
        qo[1] = d01;
        qo[2] = d01 * C2;
        qo[3] = d01 * d23;
        qo[4] = qo[3] * C4;
        qo[5] = qo[3] * d45;
        qo[6] = qo[5] * C6;
        qo[7] = qo[5] * d67;
        qo[0] = (C1 * d23) * (d45 * d67);

        // gates for this thread's single column (tree-structured)
        float gf, gi, gg, go;
        {
            float a0, a1;
            a0 = fmaf(WG0[0].x, qo[0], bgc[0]);  a0 = fmaf(WG0[0].y, qo[1], a0);
            a0 = fmaf(WG0[0].z, qo[2], a0);      a0 = fmaf(WG0[0].w, qo[3], a0);
            a1 = WG1[0].x * qo[4];               a1 = fmaf(WG1[0].y, qo[5], a1);
            a1 = fmaf(WG1[0].z, qo[6], a1);      a1 = fmaf(WG1[0].w, qo[7], a1);
            gf = a0 + a1;
            a0 = fmaf(WG0[1].x, qo[0], bgc[1]);  a0 = fmaf(WG0[1].y, qo[1], a0);
            a0 = fmaf(WG0[1].z, qo[2], a0);      a0 = fmaf(WG0[1].w, qo[3], a0);
            a1 = WG1[1].x * qo[4];               a1 = fmaf(WG1[1].y, qo[5], a1);
            a1 = fmaf(WG1[1].z, qo[6], a1);      a1 = fmaf(WG1[1].w, qo[7], a1);
            gi = a0 + a1;
            a0 = fmaf(WG0[2].x, qo[0], bgc[2]);  a0 = fmaf(WG0[2].y, qo[1], a0);
            a0 = fmaf(WG0[2].z, qo[2], a0);      a0 = fmaf(WG0[2].w, qo[3], a0);
            a1 = WG1[2].x * qo[4];               a1 = fmaf(WG1[2].y, qo[5], a1);
            a1 = fmaf(WG1[2].z, qo[6], a1);      a1 = fmaf(WG1[2].w, qo[7], a1);
            gg = a0 + a1;
            a0 = fmaf(WG0[3].x, qo[0], bgc[3]);  a0 = fmaf(WG0[3].y, qo[1], a0);
            a0 = fmaf(WG0[3].z, qo[2], a0);      a0 = fmaf(WG0[3].w, qo[3], a0);
            a1 = WG1[3].x * qo[4];               a1 = fmaf(WG1[3].y, qo[5], a1);
            a1 = fmaf(WG1[3].z, qo[6], a1);      a1 = fmaf(WG1[3].w, qo[7], a1);
            go = a0 + a1;
        }

        // LSTM pointwise, parallel form (inf-safe, no clamp):
        // sf,si,so = sigmoid; tg = tanh(g); cn = sf*c + si*tg; h = so*tanh(cn)
        const float sf = rcp_f(1.f + __expf(-gf));
        const float si = rcp_f(1.f + __expf(-gi));
        const float so = rcp_f(1.f + __expf(-go));
        const float tg = 1.f - 2.f * rcp_f(__expf(2.f * gg) + 1.f);
        const float cn = fmaf(sf, c, si * tg);
        const float th = 1.f - 2.f * rcp_f(__expf(2.f * cn) + 1.f);
        const float h  = so * th;
        c = cn;

        *outp = h;
        outp += BATCH * HID;

        hbuf[(t + 1) & 1][cg] = h;   // publish new h for all waves
        __syncthreads();             // single barrier per step
    }

    const size_t base = (size_t)T_STEPS * BATCH * HID;
    const float hfin = hbuf[T_STEPS & 1][cg];
    out[base + b * HID + cg] = hfin;
    out[base + BATCH * HID + b * HID + cg] = c;
}

extern "C" void kernel_launch(void* const* d_in, const int* in_sizes, int n_in,
                              void* d_out, int out_size, void* d_ws, size_t ws_size,
                              hipStream_t stream) {
    const float* x   = (const float*)d_in[0];   // (512,128,256)
    const float* hx  = (const float*)d_in[1];   // (128,256)
    const float* cx  = (const float*)d_in[2];   // (128,256)
    const float* Wp  = (const float*)d_in[3];   // (8,512)
    const float* qp  = (const float*)d_in[4];   // (8,)
    const float* Wg  = (const float*)d_in[5];   // (1024,8)
    const float* bg  = (const float*)d_in[6];   // (1024,)
    float* out = (float*)d_out;
    float* px  = (float*)d_ws;                  // 128*512*8 floats = 2 MB

    qlstm_projx<<<(T_STEPS * BATCH) / 4, 256, 0, stream>>>(x, Wp, qp, px);
    qlstm_seq<<<BATCH, 256, 0, stream>>>(hx, cx, Wp, Wg, bg, px, out);
}